// Round 9
// baseline (326.020 us; speedup 1.0000x reference)
//
#include <hip/hip_runtime.h>
#include <math.h>

// SchNet interaction, MFMA bf16-split, 2-dispatch design (K3 fused into K2).
// Nb=8, Na=1024, Nnbh=64, A=F=128, S=50.

#define RCUT  5.0f
#define LOG2F_ 0.69314718055994530942f

typedef __bf16 bf16x8_t __attribute__((ext_vector_type(8)));
typedef float  f32x4_t  __attribute__((ext_vector_type(4)));

static __device__ __forceinline__ float sspf(float x) {
    return fmaxf(x, 0.0f) + __logf(1.0f + __expf(-fabsf(x))) - LOG2F_;
}
static __device__ __forceinline__ unsigned pack2h(__bf16 a, __bf16 b) {
    union { __bf16 h[2]; unsigned u; } un; un.h[0] = a; un.h[1] = b; return un.u;
}
static __device__ __forceinline__ unsigned pack2f(float a, float b) {
    return pack2h((__bf16)a, (__bf16)b);
}

// ---------------------------------------------------------------------------
// K1: y = x @ W_in2f^T (bf16 hi/lo split MFMA, W converted inline) + prep
// side job into ws:
//   prep u32 layout: W1B[128][32] @0 (bf16 pairs, K 50->64 zero-pad),
//                    W2B[128][64] @4096 (bf16 pairs),
//                    WT1 fp32[128k][128f] @12288 (W_f2out transposed),
//                    WT2 fp32[128k][128f] @28672 (W_dense transposed).
// Grid 512 x 256; side-job items 45056 < 131072 threads.
// ---------------------------------------------------------------------------
__global__ __launch_bounds__(256, 4) void k1_prep_kernel(
    const float* __restrict__ x, const float* __restrict__ Wf,  // [128][128] fp32
    float* __restrict__ yout,
    const float* __restrict__ W1, const float* __restrict__ W2,
    const float* __restrict__ Wb,   // W_f2out
    const float* __restrict__ Wc,   // W_dense
    unsigned* __restrict__ prep)
{
    __shared__ __bf16 Ah[16 * 136];
    __shared__ __bf16 Al[16 * 136];

    const int t = threadIdx.x;
    const int atom0 = blockIdx.x * 16;
    const int l = t & 63, m = l & 15, q = l >> 4;
    const int w = t >> 6;
    const int f0 = 32 * w + m;
    const int f1 = f0 + 16;

    // ---- prep side job: one item per thread ----
    {
        int i = blockIdx.x * 256 + t;
        if (i < 4096) {                       // W1B: [g][32]u32, K-pad to 64
            int g = i >> 5, u = i & 31, k = 2 * u;
            float a = (k < 50)     ? W1[g * 50 + k]     : 0.0f;
            float b = (k + 1 < 50) ? W1[g * 50 + k + 1] : 0.0f;
            prep[i] = pack2f(a, b);
        } else if (i < 12288) {               // W2B single bf16
            int j = i - 4096;
            float2 wv = ((const float2*)W2)[j];
            prep[i] = pack2f(wv.x, wv.y);
        } else if (i < 28672) {               // WT1 = W_f2out^T fp32
            int j = i - 12288;                // j = k*128 + f
            int k = j >> 7, f = j & 127;
            ((float*)prep)[12288 + j] = Wb[f * 128 + k];
        } else if (i < 45056) {               // WT2 = W_dense^T fp32
            int j = i - 28672;
            int k = j >> 7, f = j & 127;
            ((float*)prep)[28672 + j] = Wc[f * 128 + k];
        }
    }

    // ---- stage x hi/lo into LDS ----
    {
        const float4* A4 = (const float4*)(x + (size_t)atom0 * 128);
        unsigned* AhU = (unsigned*)Ah;
        unsigned* AlU = (unsigned*)Al;
        #pragma unroll
        for (int r = 0; r < 2; ++r) {
            int lin4 = r * 256 + t;
            int a = lin4 >> 5, k4 = lin4 & 31;
            float4 xv = A4[lin4];
            __bf16 h0=(__bf16)xv.x, h1=(__bf16)xv.y, h2=(__bf16)xv.z, h3=(__bf16)xv.w;
            int idx = a * 68 + 2 * k4;
            AhU[idx]     = pack2h(h0, h1);
            AhU[idx + 1] = pack2h(h2, h3);
            AlU[idx]     = pack2f(xv.x - (float)h0, xv.y - (float)h1);
            AlU[idx + 1] = pack2f(xv.z - (float)h2, xv.w - (float)h3);
        }
    }
    __syncthreads();

    f32x4_t acc0 = {0.f, 0.f, 0.f, 0.f};
    f32x4_t acc1 = {0.f, 0.f, 0.f, 0.f};
    #pragma unroll
    for (int kk = 0; kk < 4; ++kk) {
        bf16x8_t ah = *(const bf16x8_t*)&Ah[m * 136 + 32 * kk + 8 * q];
        bf16x8_t al = *(const bf16x8_t*)&Al[m * 136 + 32 * kk + 8 * q];
        #pragma unroll
        for (int ftl = 0; ftl < 2; ++ftl) {
            const float* wr = Wf + (size_t)(ftl ? f1 : f0) * 128 + 32 * kk + 8 * q;
            float4 wa = *(const float4*)wr;
            float4 wb4 = *(const float4*)(wr + 4);
            float wv[8] = {wa.x, wa.y, wa.z, wa.w, wb4.x, wb4.y, wb4.z, wb4.w};
            union { __bf16 h[8]; bf16x8_t v8; } wh, wl;
            #pragma unroll
            for (int k = 0; k < 8; ++k) {
                __bf16 hi = (__bf16)wv[k];
                wh.h[k] = hi;
                wl.h[k] = (__bf16)(wv[k] - (float)hi);
            }
            f32x4_t& acc = ftl ? acc1 : acc0;
            acc = __builtin_amdgcn_mfma_f32_16x16x32_bf16(ah, wh.v8, acc, 0, 0, 0);
            acc = __builtin_amdgcn_mfma_f32_16x16x32_bf16(ah, wl.v8, acc, 0, 0, 0);
            acc = __builtin_amdgcn_mfma_f32_16x16x32_bf16(al, wh.v8, acc, 0, 0, 0);
        }
    }
    #pragma unroll
    for (int r = 0; r < 4; ++r) {
        size_t row = (size_t)(atom0 + 4 * q + r) * 128;
        yout[row + f0] = acc0[r];
        yout[row + f1] = acc1[r];
    }
}

// ---------------------------------------------------------------------------
// K2: interaction + FUSED output layers. 1 atom/block, 256 thr = 4 waves.
// Phase A/B: f-split MFMA (R8-verified). Epilogue: v row -> LDS -> two fp32
// matvecs with transposed L2-hot weights -> d_out.
// LDS 36352 B static -> 4 blocks/CU.
// ---------------------------------------------------------------------------
__global__ __launch_bounds__(256, 4) void interaction_kernel(
    const float* __restrict__ rij, const int* __restrict__ nbrs,
    const float* __restrict__ mask, const float* __restrict__ fij,
    const float* __restrict__ b1, const float* __restrict__ b2,
    const unsigned* __restrict__ W1B,   // [128][32] u32 (bf16 pairs, K=64 pad)
    const unsigned* __restrict__ W2B,   // [128][64] u32 (bf16 pairs)
    const float* __restrict__ WT1,      // [128k][128f] fp32 (W_f2out^T)
    const float* __restrict__ b3,       // b_f2out
    const float* __restrict__ WT2,      // [128k][128f] fp32 (W_dense^T)
    const float* __restrict__ b4,       // b_dense
    const float* __restrict__ y, float* __restrict__ out)
{
    __shared__ __bf16 Hh[64 * 136];
    __shared__ __bf16 Hl[64 * 136];
    __shared__ float  cb[64];
    __shared__ int    nb[64];
    __shared__ float  vv[128];
    __shared__ float  tt[128];

    const int t  = threadIdx.x;
    const int a  = blockIdx.x;
    const int bi = a >> 10;
    const int p0 = a * 64;
    const int w = t >> 6, l = t & 63, m = l & 15, q = l >> 4;
    const int f0 = 32 * w + m;
    const int f1 = f0 + 16;

    if (t < 64) {
        float r = rij[p0 + t];
        cb[t] = (r <= RCUT) ? mask[p0 + t] : 0.0f;
        nb[t] = (bi << 10) + nbrs[p0 + t];
    }

    const float bb1_0 = b1[f0], bb1_1 = b1[f1];
    const float bb2_0 = b2[f0], bb2_1 = b2[f1];

    // W1 B-frags for this wave's g columns
    bf16x8_t w1f00 = *(const bf16x8_t*)(W1B + f0 * 32 + 4 * q);
    bf16x8_t w1f01 = *(const bf16x8_t*)(W1B + f0 * 32 + 16 + 4 * q);
    bf16x8_t w1f10 = *(const bf16x8_t*)(W1B + f1 * 32 + 4 * q);
    bf16x8_t w1f11 = *(const bf16x8_t*)(W1B + f1 * 32 + 16 + 4 * q);

    // ---- phase A: H[n][g] = ssp(fij @ W1^T + b1) ----
    #pragma unroll 1
    for (int mt = 0; mt < 4; ++mt) {
        const float* frow = fij + (size_t)(p0 + 16 * mt + m) * 50;
        float kv[16];
        #pragma unroll
        for (int j2 = 0; j2 < 4; ++j2) {
            float2 xv = *(const float2*)(frow + 8 * q + 2 * j2);
            kv[2 * j2] = xv.x; kv[2 * j2 + 1] = xv.y;
        }
        #pragma unroll
        for (int j2 = 0; j2 < 4; ++j2) {
            int k = 32 + 8 * q + 2 * j2;
            float2 xv = make_float2(0.f, 0.f);
            if (k < 50) xv = *(const float2*)(frow + k);
            kv[8 + 2 * j2] = xv.x; kv[9 + 2 * j2] = xv.y;
        }
        union { __bf16 h[16]; bf16x8_t v8[2]; } uh, ul;
        #pragma unroll
        for (int k = 0; k < 16; ++k) {
            __bf16 hi = (__bf16)kv[k];
            uh.h[k] = hi;
            ul.h[k] = (__bf16)(kv[k] - (float)hi);
        }
        f32x4_t acc0 = {bb1_0, bb1_0, bb1_0, bb1_0};
        f32x4_t acc1 = {bb1_1, bb1_1, bb1_1, bb1_1};
        acc0 = __builtin_amdgcn_mfma_f32_16x16x32_bf16(uh.v8[0], w1f00, acc0, 0, 0, 0);
        acc0 = __builtin_amdgcn_mfma_f32_16x16x32_bf16(ul.v8[0], w1f00, acc0, 0, 0, 0);
        acc0 = __builtin_amdgcn_mfma_f32_16x16x32_bf16(uh.v8[1], w1f01, acc0, 0, 0, 0);
        acc0 = __builtin_amdgcn_mfma_f32_16x16x32_bf16(ul.v8[1], w1f01, acc0, 0, 0, 0);
        acc1 = __builtin_amdgcn_mfma_f32_16x16x32_bf16(uh.v8[0], w1f10, acc1, 0, 0, 0);
        acc1 = __builtin_amdgcn_mfma_f32_16x16x32_bf16(ul.v8[0], w1f10, acc1, 0, 0, 0);
        acc1 = __builtin_amdgcn_mfma_f32_16x16x32_bf16(uh.v8[1], w1f11, acc1, 0, 0, 0);
        acc1 = __builtin_amdgcn_mfma_f32_16x16x32_bf16(ul.v8[1], w1f11, acc1, 0, 0, 0);
        #pragma unroll
        for (int r = 0; r < 4; ++r) {
            int n = 16 * mt + 4 * q + r;
            float h0v = sspf(acc0[r]);
            float h1v = sspf(acc1[r]);
            __bf16 hh0 = (__bf16)h0v, hh1 = (__bf16)h1v;
            Hh[n * 136 + f0] = hh0;
            Hl[n * 136 + f0] = (__bf16)(h0v - (float)hh0);
            Hh[n * 136 + f1] = hh1;
            Hl[n * 136 + f1] = (__bf16)(h1v - (float)hh1);
        }
    }
    __syncthreads();   // H + cb/nb handoff

    // ---- phase B: Wm = H @ W2^T + b2, fused gather/aggregate ----
    float pv0 = 0.0f, pv1 = 0.0f;
    #pragma unroll 1
    for (int mt = 0; mt < 4; ++mt) {
        f32x4_t acc0 = {bb2_0, bb2_0, bb2_0, bb2_0};
        f32x4_t acc1 = {bb2_1, bb2_1, bb2_1, bb2_1};
        #pragma unroll
        for (int kq = 0; kq < 4; ++kq) {
            int hoff = (16 * mt + m) * 136 + 32 * kq + 8 * q;
            bf16x8_t hh = *(const bf16x8_t*)&Hh[hoff];
            bf16x8_t hl = *(const bf16x8_t*)&Hl[hoff];
            bf16x8_t w20 = *(const bf16x8_t*)(W2B + f0 * 64 + 16 * kq + 4 * q);
            bf16x8_t w21 = *(const bf16x8_t*)(W2B + f1 * 64 + 16 * kq + 4 * q);
            acc0 = __builtin_amdgcn_mfma_f32_16x16x32_bf16(hh, w20, acc0, 0, 0, 0);
            acc0 = __builtin_amdgcn_mfma_f32_16x16x32_bf16(hl, w20, acc0, 0, 0, 0);
            acc1 = __builtin_amdgcn_mfma_f32_16x16x32_bf16(hh, w21, acc1, 0, 0, 0);
            acc1 = __builtin_amdgcn_mfma_f32_16x16x32_bf16(hl, w21, acc1, 0, 0, 0);
        }
        #pragma unroll
        for (int r = 0; r < 4; ++r) {
            int n = 16 * mt + 4 * q + r;
            float cn = cb[n];
            const float* yrow = y + (size_t)nb[n] * 128;
            pv0 = fmaf(cn * yrow[f0], acc0[r], pv0);
            pv1 = fmaf(cn * yrow[f1], acc1[r], pv1);
        }
    }
    pv0 += __shfl_xor(pv0, 16);
    pv0 += __shfl_xor(pv0, 32);
    pv1 += __shfl_xor(pv1, 16);
    pv1 += __shfl_xor(pv1, 32);
    if (l < 16) {
        vv[f0] = pv0;
        vv[f1] = pv1;
    }
    __syncthreads();

    // ---- fused K3: out = ssp(ssp(v@W_f2out^T+b3)) @ W_dense^T + b4 ----
    if (t < 128) {
        float acc = b3[t];
        #pragma unroll 8
        for (int k = 0; k < 128; ++k)
            acc = fmaf(vv[k], WT1[k * 128 + t], acc);   // vv: LDS broadcast; WT1: coalesced
        tt[t] = sspf(sspf(acc));
    }
    __syncthreads();
    if (t < 128) {
        float acc = b4[t];
        #pragma unroll 8
        for (int k = 0; k < 128; ++k)
            acc = fmaf(tt[k], WT2[k * 128 + t], acc);
        out[(size_t)a * 128 + t] = acc;
    }
}

// ---------------------------------------------------------------------------
extern "C" void kernel_launch(void* const* d_in, const int* in_sizes, int n_in,
                              void* d_out, int out_size, void* d_ws, size_t ws_size,
                              hipStream_t stream) {
    const float* x        = (const float*)d_in[0];
    const float* rij      = (const float*)d_in[1];
    const int*   nbrs     = (const int*)  d_in[2];
    const float* mask     = (const float*)d_in[3];
    const float* fij      = (const float*)d_in[4];
    const float* W_in2f   = (const float*)d_in[5];
    const float* W_f1     = (const float*)d_in[6];
    const float* b_f1     = (const float*)d_in[7];
    const float* W_f2     = (const float*)d_in[8];
    const float* b_f2     = (const float*)d_in[9];
    const float* W_f2out  = (const float*)d_in[10];
    const float* b_f2out  = (const float*)d_in[11];
    const float* W_dense  = (const float*)d_in[12];
    const float* b_dense  = (const float*)d_in[13];
    float* out = (float*)d_out;

    // ws: y [8192][128] f32 @0 (4 MB) | prep 176 KB @4 MB.
    float*    y    = (float*)d_ws;
    unsigned* prep = (unsigned*)((char*)d_ws + (4u << 20));
    const unsigned* W1B = prep;
    const unsigned* W2B = prep + 4096;
    const float*    WT1 = (const float*)(prep + 12288);
    const float*    WT2 = (const float*)(prep + 28672);

    // K1: y = x @ W_in2f^T  (+ prep side job)
    k1_prep_kernel<<<512, 256, 0, stream>>>(
        x, W_in2f, y, W_f1, W_f2, W_f2out, W_dense, prep);
    // K2: filter net + cutoff + gather + aggregate + output layers -> d_out
    interaction_kernel<<<8192, 256, 0, stream>>>(
        rij, nbrs, mask, fij, b_f1, b_f2, W1B, W2B,
        WT1, b_f2out, WT2, b_dense, y, out);
}

// Round 10
// 261.989 us; speedup vs baseline: 1.2444x; 1.2444x over previous
//
#include <hip/hip_runtime.h>
#include <math.h>

// SchNet interaction, MFMA bf16-split, swizzled-weight design.
// Nb=8, Na=1024, Nnbh=64, A=F=128, S=50.
// prep u32 layout (all weight frags in fragment-linear "swizzled" order so a
// wave's 64 lanes read 1 KB contiguous per fragment load):
//   W1S  @0      (4096):  [w][ft][kh][l][4]   W_f1 bf16, K 50->64 pad
//   W2S  @4096   (8192):  [w][ft][kq][l][4]   W_f2 bf16
//   F2O_h @12288 (8192), F2O_l @20480 (8192)  W_f2out hi/lo split, swizzled
//   DEN_h @28672 (8192), DEN_l @36864 (8192)  W_dense  hi/lo split, swizzled
// where f = 32w + 16ft + m, u32-col c = kh*16+4q+j (W1) / 16kq+4q+j, l=16q+m.

#define RCUT  5.0f
#define LOG2F_ 0.69314718055994530942f

typedef __bf16 bf16x8_t __attribute__((ext_vector_type(8)));
typedef float  f32x4_t  __attribute__((ext_vector_type(4)));

static __device__ __forceinline__ float sspf(float x) {
    return fmaxf(x, 0.0f) + __logf(1.0f + __expf(-fabsf(x))) - LOG2F_;
}
static __device__ __forceinline__ unsigned pack2h(__bf16 a, __bf16 b) {
    union { __bf16 h[2]; unsigned u; } un; un.h[0] = a; un.h[1] = b; return un.u;
}
static __device__ __forceinline__ unsigned pack2f(float a, float b) {
    return pack2h((__bf16)a, (__bf16)b);
}

// ---------------------------------------------------------------------------
// K1: y = x @ W_in2f^T (bf16 hi/lo MFMA, W converted inline) + prep side job.
// Grid 512 x 256; side-job items 45056 < 131072 threads.
// ---------------------------------------------------------------------------
__global__ __launch_bounds__(256, 4) void k1_prep_kernel(
    const float* __restrict__ x, const float* __restrict__ Wf,  // [128][128] fp32
    float* __restrict__ yout,
    const float* __restrict__ W1, const float* __restrict__ W2,
    const float* __restrict__ Wb,   // W_f2out
    const float* __restrict__ Wc,   // W_dense
    unsigned* __restrict__ prep)
{
    __shared__ __bf16 Ah[16 * 136];
    __shared__ __bf16 Al[16 * 136];

    const int t = threadIdx.x;
    const int atom0 = blockIdx.x * 16;
    const int l = t & 63, m = l & 15, q = l >> 4;
    const int w = t >> 6;
    const int f0 = 32 * w + m;
    const int f1 = f0 + 16;

    // ---- prep side job: one swizzled item per thread ----
    {
        int i = blockIdx.x * 256 + t;
        if (i < 4096) {                        // W1S
            int sw = i >> 10, ft = (i >> 9) & 1, kh = (i >> 8) & 1;
            int sl = (i >> 2) & 63, j = i & 3;
            int sq = sl >> 4, sm = sl & 15;
            int f = 32 * sw + 16 * ft + sm;
            int c = kh * 16 + 4 * sq + j;
            int k0 = 2 * c, k1 = 2 * c + 1;
            float a = (k0 < 50) ? W1[f * 50 + k0] : 0.0f;
            float b = (k1 < 50) ? W1[f * 50 + k1] : 0.0f;
            prep[i] = pack2f(a, b);
        } else if (i < 12288) {                // W2S
            int s = i - 4096;
            int sw = s >> 11, ft = (s >> 10) & 1, kq = (s >> 8) & 3;
            int sl = (s >> 2) & 63, j = s & 3;
            int sq = sl >> 4, sm = sl & 15;
            int f = 32 * sw + 16 * ft + sm;
            int c = 16 * kq + 4 * sq + j;
            float2 wv = ((const float2*)W2)[f * 64 + c];
            prep[i] = pack2f(wv.x, wv.y);
        } else if (i < 45056) {                // f2out / dense, hi+lo swizzled
            int s = i - 12288;
            int L = s >> 14;                   // 0: f2out, 1: dense
            int r = s & 16383;
            int hl = r >> 13;                  // 0: hi, 1: lo
            int e = r & 8191;
            int sw = e >> 11, ft = (e >> 10) & 1, kq = (e >> 8) & 3;
            int sl = (e >> 2) & 63, j = e & 3;
            int sq = sl >> 4, sm = sl & 15;
            int f = 32 * sw + 16 * ft + sm;
            int c = 16 * kq + 4 * sq + j;
            const float* src = L ? Wc : Wb;
            float2 wv = ((const float2*)src)[f * 64 + c];
            if (hl == 0) {
                prep[i] = pack2h((__bf16)wv.x, (__bf16)wv.y);
            } else {
                __bf16 h0 = (__bf16)wv.x, h1 = (__bf16)wv.y;
                prep[i] = pack2f(wv.x - (float)h0, wv.y - (float)h1);
            }
        }
    }

    // ---- stage x hi/lo into LDS ----
    {
        const float4* A4 = (const float4*)(x + (size_t)atom0 * 128);
        unsigned* AhU = (unsigned*)Ah;
        unsigned* AlU = (unsigned*)Al;
        #pragma unroll
        for (int r = 0; r < 2; ++r) {
            int lin4 = r * 256 + t;
            int a = lin4 >> 5, k4 = lin4 & 31;
            float4 xv = A4[lin4];
            __bf16 h0=(__bf16)xv.x, h1=(__bf16)xv.y, h2=(__bf16)xv.z, h3=(__bf16)xv.w;
            int idx = a * 68 + 2 * k4;
            AhU[idx]     = pack2h(h0, h1);
            AhU[idx + 1] = pack2h(h2, h3);
            AlU[idx]     = pack2f(xv.x - (float)h0, xv.y - (float)h1);
            AlU[idx + 1] = pack2f(xv.z - (float)h2, xv.w - (float)h3);
        }
    }
    __syncthreads();

    f32x4_t acc0 = {0.f, 0.f, 0.f, 0.f};
    f32x4_t acc1 = {0.f, 0.f, 0.f, 0.f};
    #pragma unroll
    for (int kk = 0; kk < 4; ++kk) {
        bf16x8_t ah = *(const bf16x8_t*)&Ah[m * 136 + 32 * kk + 8 * q];
        bf16x8_t al = *(const bf16x8_t*)&Al[m * 136 + 32 * kk + 8 * q];
        #pragma unroll
        for (int ftl = 0; ftl < 2; ++ftl) {
            const float* wr = Wf + (size_t)(ftl ? f1 : f0) * 128 + 32 * kk + 8 * q;
            float4 wa = *(const float4*)wr;
            float4 wb4 = *(const float4*)(wr + 4);
            float wv[8] = {wa.x, wa.y, wa.z, wa.w, wb4.x, wb4.y, wb4.z, wb4.w};
            union { __bf16 h[8]; bf16x8_t v8; } wh, wl;
            #pragma unroll
            for (int k = 0; k < 8; ++k) {
                __bf16 hi = (__bf16)wv[k];
                wh.h[k] = hi;
                wl.h[k] = (__bf16)(wv[k] - (float)hi);
            }
            f32x4_t& acc = ftl ? acc1 : acc0;
            acc = __builtin_amdgcn_mfma_f32_16x16x32_bf16(ah, wh.v8, acc, 0, 0, 0);
            acc = __builtin_amdgcn_mfma_f32_16x16x32_bf16(ah, wl.v8, acc, 0, 0, 0);
            acc = __builtin_amdgcn_mfma_f32_16x16x32_bf16(al, wh.v8, acc, 0, 0, 0);
        }
    }
    #pragma unroll
    for (int r = 0; r < 4; ++r) {
        size_t row = (size_t)(atom0 + 4 * q + r) * 128;
        yout[row + f0] = acc0[r];
        yout[row + f1] = acc1[r];
    }
}

// ---------------------------------------------------------------------------
// K2 interaction (R8 structure + swizzled coalesced weight loads).
// 1 atom/block, 256 thr = 4 waves, ONE barrier, LDS 35328 B -> 4 blocks/CU.
// ---------------------------------------------------------------------------
__global__ __launch_bounds__(256, 4) void interaction_kernel(
    const float* __restrict__ rij, const int* __restrict__ nbrs,
    const float* __restrict__ mask, const float* __restrict__ fij,
    const float* __restrict__ b1, const float* __restrict__ b2,
    const unsigned* __restrict__ W1S,   // swizzled [4][2][2][64][4] u32
    const unsigned* __restrict__ W2S,   // swizzled [4][2][4][64][4] u32
    const float* __restrict__ y, float* __restrict__ v)
{
    __shared__ __bf16 Hh[64 * 136];
    __shared__ __bf16 Hl[64 * 136];
    __shared__ float  cb[64];
    __shared__ int    nb[64];

    const int t  = threadIdx.x;
    const int a  = blockIdx.x;
    const int bi = a >> 10;
    const int p0 = a * 64;
    const int w = t >> 6, l = t & 63, m = l & 15, q = l >> 4;
    const int f0 = 32 * w + m;
    const int f1 = f0 + 16;

    if (t < 64) {
        float r = rij[p0 + t];
        cb[t] = (r <= RCUT) ? mask[p0 + t] : 0.0f;
        nb[t] = (bi << 10) + nbrs[p0 + t];
    }

    const float bb1_0 = b1[f0], bb1_1 = b1[f1];
    const float bb2_0 = b2[f0], bb2_1 = b2[f1];

    // W1 B-frags: fully coalesced (1 KB/instruction)
    bf16x8_t w1f00 = *(const bf16x8_t*)(W1S + ((w * 2 + 0) * 2 + 0) * 256 + l * 4);
    bf16x8_t w1f01 = *(const bf16x8_t*)(W1S + ((w * 2 + 0) * 2 + 1) * 256 + l * 4);
    bf16x8_t w1f10 = *(const bf16x8_t*)(W1S + ((w * 2 + 1) * 2 + 0) * 256 + l * 4);
    bf16x8_t w1f11 = *(const bf16x8_t*)(W1S + ((w * 2 + 1) * 2 + 1) * 256 + l * 4);

    // ---- phase A: H[n][g] = ssp(fij @ W1^T + b1) ----
    #pragma unroll 1
    for (int mt = 0; mt < 4; ++mt) {
        const float* frow = fij + (size_t)(p0 + 16 * mt + m) * 50;
        float kv[16];
        #pragma unroll
        for (int j2 = 0; j2 < 4; ++j2) {
            float2 xv = *(const float2*)(frow + 8 * q + 2 * j2);
            kv[2 * j2] = xv.x; kv[2 * j2 + 1] = xv.y;
        }
        #pragma unroll
        for (int j2 = 0; j2 < 4; ++j2) {
            int k = 32 + 8 * q + 2 * j2;
            float2 xv = make_float2(0.f, 0.f);
            if (k < 50) xv = *(const float2*)(frow + k);
            kv[8 + 2 * j2] = xv.x; kv[9 + 2 * j2] = xv.y;
        }
        union { __bf16 h[16]; bf16x8_t v8[2]; } uh, ul;
        #pragma unroll
        for (int k = 0; k < 16; ++k) {
            __bf16 hi = (__bf16)kv[k];
            uh.h[k] = hi;
            ul.h[k] = (__bf16)(kv[k] - (float)hi);
        }
        f32x4_t acc0 = {bb1_0, bb1_0, bb1_0, bb1_0};
        f32x4_t acc1 = {bb1_1, bb1_1, bb1_1, bb1_1};
        acc0 = __builtin_amdgcn_mfma_f32_16x16x32_bf16(uh.v8[0], w1f00, acc0, 0, 0, 0);
        acc0 = __builtin_amdgcn_mfma_f32_16x16x32_bf16(ul.v8[0], w1f00, acc0, 0, 0, 0);
        acc0 = __builtin_amdgcn_mfma_f32_16x16x32_bf16(uh.v8[1], w1f01, acc0, 0, 0, 0);
        acc0 = __builtin_amdgcn_mfma_f32_16x16x32_bf16(ul.v8[1], w1f01, acc0, 0, 0, 0);
        acc1 = __builtin_amdgcn_mfma_f32_16x16x32_bf16(uh.v8[0], w1f10, acc1, 0, 0, 0);
        acc1 = __builtin_amdgcn_mfma_f32_16x16x32_bf16(ul.v8[0], w1f10, acc1, 0, 0, 0);
        acc1 = __builtin_amdgcn_mfma_f32_16x16x32_bf16(uh.v8[1], w1f11, acc1, 0, 0, 0);
        acc1 = __builtin_amdgcn_mfma_f32_16x16x32_bf16(ul.v8[1], w1f11, acc1, 0, 0, 0);
        #pragma unroll
        for (int r = 0; r < 4; ++r) {
            int n = 16 * mt + 4 * q + r;
            float h0v = sspf(acc0[r]);
            float h1v = sspf(acc1[r]);
            __bf16 hh0 = (__bf16)h0v, hh1 = (__bf16)h1v;
            Hh[n * 136 + f0] = hh0;
            Hl[n * 136 + f0] = (__bf16)(h0v - (float)hh0);
            Hh[n * 136 + f1] = hh1;
            Hl[n * 136 + f1] = (__bf16)(h1v - (float)hh1);
        }
    }
    __syncthreads();   // the ONLY barrier

    // ---- phase B: Wm = H @ W2^T + b2, fused gather/aggregate ----
    float pv0 = 0.0f, pv1 = 0.0f;
    #pragma unroll 1
    for (int mt = 0; mt < 4; ++mt) {
        f32x4_t acc0 = {bb2_0, bb2_0, bb2_0, bb2_0};
        f32x4_t acc1 = {bb2_1, bb2_1, bb2_1, bb2_1};
        #pragma unroll
        for (int kq = 0; kq < 4; ++kq) {
            int hoff = (16 * mt + m) * 136 + 32 * kq + 8 * q;
            bf16x8_t hh = *(const bf16x8_t*)&Hh[hoff];
            bf16x8_t hl = *(const bf16x8_t*)&Hl[hoff];
            bf16x8_t w20 = *(const bf16x8_t*)(W2S + ((w * 2 + 0) * 4 + kq) * 256 + l * 4);
            bf16x8_t w21 = *(const bf16x8_t*)(W2S + ((w * 2 + 1) * 4 + kq) * 256 + l * 4);
            acc0 = __builtin_amdgcn_mfma_f32_16x16x32_bf16(hh, w20, acc0, 0, 0, 0);
            acc0 = __builtin_amdgcn_mfma_f32_16x16x32_bf16(hl, w20, acc0, 0, 0, 0);
            acc1 = __builtin_amdgcn_mfma_f32_16x16x32_bf16(hh, w21, acc1, 0, 0, 0);
            acc1 = __builtin_amdgcn_mfma_f32_16x16x32_bf16(hl, w21, acc1, 0, 0, 0);
        }
        #pragma unroll
        for (int r = 0; r < 4; ++r) {
            int n = 16 * mt + 4 * q + r;
            float cn = cb[n];
            const float* yrow = y + (size_t)nb[n] * 128;
            pv0 = fmaf(cn * yrow[f0], acc0[r], pv0);
            pv1 = fmaf(cn * yrow[f1], acc1[r], pv1);
        }
    }
    pv0 += __shfl_xor(pv0, 16);
    pv0 += __shfl_xor(pv0, 32);
    pv1 += __shfl_xor(pv1, 16);
    pv1 += __shfl_xor(pv1, 32);
    if (l < 16) {
        v[(size_t)a * 128 + f0] = pv0;
        v[(size_t)a * 128 + f1] = pv1;
    }
}

// ---------------------------------------------------------------------------
// K3: two chained dense layers, swizzled coalesced weight loads.
// ---------------------------------------------------------------------------
__global__ __launch_bounds__(256, 4) void mgemm2_kernel(
    const float* A,
    const unsigned* __restrict__ W1h, const unsigned* __restrict__ W1l,
    const float* __restrict__ bias1, int nssp1,
    const unsigned* __restrict__ W2h, const unsigned* __restrict__ W2l,
    const float* __restrict__ bias2, int nssp2,
    float* C)
{
    extern __shared__ float smf[];
    __bf16* Ah = (__bf16*)smf;              // [16][136]
    __bf16* Al = (__bf16*)(smf + 1088);
    unsigned* AhU = (unsigned*)Ah;
    unsigned* AlU = (unsigned*)Al;

    const int t = threadIdx.x;
    const int atom0 = blockIdx.x * 16;
    const int w = t >> 6, l = t & 63, m = l & 15, q = l >> 4;

    {
        const float4* A4 = (const float4*)(A + (size_t)atom0 * 128);
        #pragma unroll
        for (int r = 0; r < 2; ++r) {
            int lin4 = r * 256 + t;
            int a = lin4 >> 5, k4 = lin4 & 31;
            float4 xv = A4[lin4];
            __bf16 h0=(__bf16)xv.x, h1=(__bf16)xv.y, h2=(__bf16)xv.z, h3=(__bf16)xv.w;
            int idx = a * 68 + 2 * k4;
            AhU[idx]     = pack2h(h0, h1);
            AhU[idx + 1] = pack2h(h2, h3);
            AlU[idx]     = pack2f(xv.x - (float)h0, xv.y - (float)h1);
            AlU[idx + 1] = pack2f(xv.z - (float)h2, xv.w - (float)h3);
        }
    }
    __syncthreads();

    bf16x8_t ah[4], al[4];
    #pragma unroll
    for (int kk = 0; kk < 4; ++kk) {
        int off = m * 136 + 32 * kk + 8 * q;
        ah[kk] = *(const bf16x8_t*)&Ah[off];
        al[kk] = *(const bf16x8_t*)&Al[off];
    }
    f32x4_t acc[2];
    int fidx[2];
    #pragma unroll
    for (int ft = 0; ft < 2; ++ft) {
        fidx[ft] = 16 * (2 * w + ft) + m;
        float b = bias1 ? bias1[fidx[ft]] : 0.0f;
        acc[ft] = (f32x4_t){b, b, b, b};
    }
    #pragma unroll
    for (int ft = 0; ft < 2; ++ft) {
        #pragma unroll
        for (int kk = 0; kk < 4; ++kk) {
            int wo = ((2 * w + ft) * 4 + kk) * 256 + l * 4;
            bf16x8_t wh = *(const bf16x8_t*)(W1h + wo);
            bf16x8_t wl = *(const bf16x8_t*)(W1l + wo);
            acc[ft] = __builtin_amdgcn_mfma_f32_16x16x32_bf16(ah[kk], wh, acc[ft], 0, 0, 0);
            acc[ft] = __builtin_amdgcn_mfma_f32_16x16x32_bf16(ah[kk], wl, acc[ft], 0, 0, 0);
            acc[ft] = __builtin_amdgcn_mfma_f32_16x16x32_bf16(al[kk], wh, acc[ft], 0, 0, 0);
        }
    }
    #pragma unroll
    for (int ft = 0; ft < 2; ++ft)
        #pragma unroll
        for (int r = 0; r < 4; ++r) {
            float o = acc[ft][r];
            if (nssp1 >= 1) o = sspf(o);
            if (nssp1 >= 2) o = sspf(o);
            acc[ft][r] = o;
        }

    __syncthreads();
    #pragma unroll
    for (int ft = 0; ft < 2; ++ft)
        #pragma unroll
        for (int r = 0; r < 4; ++r) {
            float o = acc[ft][r];
            __bf16 hh = (__bf16)o;
            Ah[(4 * q + r) * 136 + fidx[ft]] = hh;
            Al[(4 * q + r) * 136 + fidx[ft]] = (__bf16)(o - (float)hh);
        }
    __syncthreads();

    #pragma unroll
    for (int kk = 0; kk < 4; ++kk) {
        int off = m * 136 + 32 * kk + 8 * q;
        ah[kk] = *(const bf16x8_t*)&Ah[off];
        al[kk] = *(const bf16x8_t*)&Al[off];
    }
    #pragma unroll
    for (int ft = 0; ft < 2; ++ft) {
        float b = bias2 ? bias2[fidx[ft]] : 0.0f;
        acc[ft] = (f32x4_t){b, b, b, b};
    }
    #pragma unroll
    for (int ft = 0; ft < 2; ++ft) {
        #pragma unroll
        for (int kk = 0; kk < 4; ++kk) {
            int wo = ((2 * w + ft) * 4 + kk) * 256 + l * 4;
            bf16x8_t wh = *(const bf16x8_t*)(W2h + wo);
            bf16x8_t wl = *(const bf16x8_t*)(W2l + wo);
            acc[ft] = __builtin_amdgcn_mfma_f32_16x16x32_bf16(ah[kk], wh, acc[ft], 0, 0, 0);
            acc[ft] = __builtin_amdgcn_mfma_f32_16x16x32_bf16(ah[kk], wl, acc[ft], 0, 0, 0);
            acc[ft] = __builtin_amdgcn_mfma_f32_16x16x32_bf16(al[kk], wh, acc[ft], 0, 0, 0);
        }
    }
    #pragma unroll
    for (int ft = 0; ft < 2; ++ft)
        #pragma unroll
        for (int r = 0; r < 4; ++r) {
            float o = acc[ft][r];
            if (nssp2 >= 1) o = sspf(o);
            if (nssp2 >= 2) o = sspf(o);
            C[(size_t)(atom0 + 4 * q + r) * 128 + fidx[ft]] = o;
        }
}

// ---------------------------------------------------------------------------
extern "C" void kernel_launch(void* const* d_in, const int* in_sizes, int n_in,
                              void* d_out, int out_size, void* d_ws, size_t ws_size,
                              hipStream_t stream) {
    const float* x        = (const float*)d_in[0];
    const float* rij      = (const float*)d_in[1];
    const int*   nbrs     = (const int*)  d_in[2];
    const float* mask     = (const float*)d_in[3];
    const float* fij      = (const float*)d_in[4];
    const float* W_in2f   = (const float*)d_in[5];
    const float* W_f1     = (const float*)d_in[6];
    const float* b_f1     = (const float*)d_in[7];
    const float* W_f2     = (const float*)d_in[8];
    const float* b_f2     = (const float*)d_in[9];
    const float* W_f2out  = (const float*)d_in[10];
    const float* b_f2out  = (const float*)d_in[11];
    const float* W_dense  = (const float*)d_in[12];
    const float* b_dense  = (const float*)d_in[13];
    float* out = (float*)d_out;

    // ws: y [8192][128] f32 @0 (4 MB) | prep 176 KB @4 MB.
    float*    y    = (float*)d_ws;
    unsigned* prep = (unsigned*)((char*)d_ws + (4u << 20));
    const unsigned* W1S   = prep;
    const unsigned* W2S   = prep + 4096;
    const unsigned* f2o_h = prep + 12288, *f2o_l = prep + 20480;
    const unsigned* den_h = prep + 28672, *den_l = prep + 36864;

    const int MG2_LDS = 2176 * 4;    // 8704 B

    // K1: y = x @ W_in2f^T  (+ swizzled prep side job)
    k1_prep_kernel<<<512, 256, 0, stream>>>(
        x, W_in2f, y, W_f1, W_f2, W_f2out, W_dense, prep);
    // K2: filter net + cutoff + gather + aggregate -> d_out (v)
    interaction_kernel<<<8192, 256, 0, stream>>>(
        rij, nbrs, mask, fij, b_f1, b_f2, W1S, W2S, y, out);
    // K3: out = ssp(ssp(v@W_f2out^T+b)) @ W_dense^T + b_dense, in-place
    mgemm2_kernel<<<512, 256, MG2_LDS, stream>>>(
        out, f2o_h, f2o_l, b_f2out, 2, den_h, den_l, b_dense, 0, out);
}